// Round 3
// baseline (3218.172 us; speedup 1.0000x reference)
//
#include <hip/hip_runtime.h>
#include <cstdio>

// ---------------------------------------------------------------------------
// GraphMessagePassing, f32. Round-3: lane-per-edge compute with
//  - activations staged COALESCED into a per-wave transposed LDS tile
//    X[16][65] (16-k chunks; +1 pad -> conflict-free column reads)
//  - inner loop: 1 ds_read_b32 (x_k, per-lane edge) feeds 64 FMAs with
//    wave-uniform weights (s_load broadcast): v_fmac v_h, s_w, v_x
//  - h[64] lane-resident (static indexing only; ~100 VGPR, no spill)
//  - layer 2 output-stationary in 16-chunks; LDS transpose; 64B-segment
//    coalesced atomics (verified semantics from round 2)
// ---------------------------------------------------------------------------

#define THREADS 256
#define WPB 4   // waves per block

__launch_bounds__(THREADS, 4)
__global__ void GraphMessagePassing_5952824672257_kernel(
    const float* __restrict__ nodef,   // [N,64]
    const float* __restrict__ edgef,   // [E,16]
    const int*   __restrict__ eidx,    // [2,E] int32
    const float* __restrict__ w1,      // [80,64] row-major
    const float* __restrict__ b1,      // [64]
    const float* __restrict__ w2,      // [64,64]
    const float* __restrict__ b2,      // [64]
    float* __restrict__ agg,           // [N,64] pre-zeroed
    int n_edges, int n_nodes)
{
    __shared__ float X[WPB][16][65];   // staged activations, [feature r][edge e]
    __shared__ float T[WPB][64][17];   // output transpose tile
    const int lane = threadIdx.x & 63;
    const int wid  = threadIdx.x >> 6;
    float (* __restrict__ Xw)[65] = X[wid];
    float (* __restrict__ Tw)[17] = T[wid];

    const long base = ((long)blockIdx.x * WPB + wid) * 64;
    const long e  = base + lane;
    const long ec = (e < n_edges) ? e : (long)n_edges - 1;

    int s = eidx[ec];
    int d = eidx[(size_t)n_edges + ec];
    if ((unsigned)s >= (unsigned)n_nodes) s = 0;
    if ((unsigned)d >= (unsigned)n_nodes) d = 0;

    // staging roles: lane supplies feature r of edge (i*4 + eg)
    const int r  = lane & 15;
    const int eg = lane >> 4;

    // row bases of the 16 edges this lane stages (one per unrolled i)
    int se[16];
    #pragma unroll
    for (int i = 0; i < 16; ++i)
        se[i] = __shfl(s, i * 4 + eg, 64);

    // ---- layer 1: h[j] = b1[j] + sum_k x[k] * w1[k][j], k = 0..79
    float h[64];
    #pragma unroll
    for (int j = 0; j < 64; ++j) h[j] = b1[j];   // uniform -> s_load

    #pragma unroll 1
    for (int kc = 0; kc < 5; ++kc) {
        if (kc < 4) {
            #pragma unroll
            for (int i = 0; i < 16; ++i)
                Xw[r][i * 4 + eg] = nodef[(size_t)se[i] * 64 + kc * 16 + r];
        } else {
            #pragma unroll
            for (int i = 0; i < 16; ++i) {
                long ei = base + i * 4 + eg;
                if (ei >= n_edges) ei = n_edges - 1;
                Xw[r][i * 4 + eg] = edgef[(size_t)ei * 16 + r];
            }
        }
        __syncthreads();
        #pragma unroll 2
        for (int r2 = 0; r2 < 16; ++r2) {
            const float xk = Xw[r2][lane];                       // conflict-free
            const float* __restrict__ wr = w1 + (kc * 16 + r2) * 64;  // uniform
            #pragma unroll
            for (int j = 0; j < 64; ++j)
                h[j] = fmaf(xk, wr[j], h[j]);                    // v_fmac v,s,v
        }
        __syncthreads();
    }
    #pragma unroll
    for (int j = 0; j < 64; ++j) h[j] = fmaxf(h[j], 0.f);

    // dst indices for the transposed scatter
    const int oc  = lane & 15;
    const int er4 = lane >> 4;
    int dgs[16];
    #pragma unroll
    for (int g = 0; g < 16; ++g)
        dgs[g] = __shfl(d, g * 4 + er4, 64);

    // ---- layer 2 in 16-output chunks + transpose + coalesced atomics
    #pragma unroll 1
    for (int ob = 0; ob < 4; ++ob) {
        float m[16];
        #pragma unroll
        for (int c = 0; c < 16; ++c) m[c] = b2[ob * 16 + c];     // uniform
        #pragma unroll
        for (int t = 0; t < 64; ++t) {
            const float hv = h[t];
            const float* __restrict__ wr = w2 + t * 64 + ob * 16;  // uniform
            #pragma unroll
            for (int c = 0; c < 16; ++c)
                m[c] = fmaf(hv, wr[c], m[c]);
        }
        #pragma unroll
        for (int c = 0; c < 16; ++c) Tw[lane][c] = m[c];
        __syncthreads();
        #pragma unroll
        for (int g = 0; g < 16; ++g) {
            const int le = g * 4 + er4;
            const float v = Tw[le][oc];
            if (base + le < n_edges)
                atomicAdd(agg + (size_t)dgs[g] * 64 + ob * 16 + oc, v);
        }
        __syncthreads();
    }
}

// Node phase: out = relu(b1 + [node, agg] @ w_u1) @ w_u2 + b_u2
__launch_bounds__(THREADS, 4)
__global__ void node_mlp_reg(
    const float* __restrict__ nodef,   // [N,64]
    const float* __restrict__ agg,     // [N,64]
    const float* __restrict__ w1,      // [128,64]
    const float* __restrict__ b1,      // [64]
    const float* __restrict__ w2,      // [64,64]
    const float* __restrict__ b2,      // [64]
    float* __restrict__ out,           // [N,64]
    int n_nodes)
{
    __shared__ float X[WPB][16][65];
    __shared__ float T[WPB][64][17];
    const int lane = threadIdx.x & 63;
    const int wid  = threadIdx.x >> 6;
    float (* __restrict__ Xw)[65] = X[wid];
    float (* __restrict__ Tw)[17] = T[wid];

    const long base = ((long)blockIdx.x * WPB + wid) * 64;

    const int r  = lane & 15;
    const int eg = lane >> 4;

    float h[64];
    #pragma unroll
    for (int j = 0; j < 64; ++j) h[j] = b1[j];

    // k = 0..127: chunks 0-3 from nodef rows, 4-7 from agg rows (contiguous)
    #pragma unroll 1
    for (int kc = 0; kc < 8; ++kc) {
        const float* __restrict__ src = (kc < 4) ? nodef : agg;
        const int ko = (kc & 3) * 16;
        #pragma unroll
        for (int i = 0; i < 16; ++i) {
            long row = base + i * 4 + eg;
            if (row >= n_nodes) row = n_nodes - 1;
            Xw[r][i * 4 + eg] = src[(size_t)row * 64 + ko + r];
        }
        __syncthreads();
        #pragma unroll 2
        for (int r2 = 0; r2 < 16; ++r2) {
            const float xk = Xw[r2][lane];
            const float* __restrict__ wr = w1 + (kc * 16 + r2) * 64;
            #pragma unroll
            for (int j = 0; j < 64; ++j)
                h[j] = fmaf(xk, wr[j], h[j]);
        }
        __syncthreads();
    }
    #pragma unroll
    for (int j = 0; j < 64; ++j) h[j] = fmaxf(h[j], 0.f);

    const int oc  = lane & 15;
    const int er4 = lane >> 4;

    #pragma unroll 1
    for (int ob = 0; ob < 4; ++ob) {
        float m[16];
        #pragma unroll
        for (int c = 0; c < 16; ++c) m[c] = b2[ob * 16 + c];
        #pragma unroll
        for (int t = 0; t < 64; ++t) {
            const float hv = h[t];
            const float* __restrict__ wr = w2 + t * 64 + ob * 16;
            #pragma unroll
            for (int c = 0; c < 16; ++c)
                m[c] = fmaf(hv, wr[c], m[c]);
        }
        #pragma unroll
        for (int c = 0; c < 16; ++c) Tw[lane][c] = m[c];
        __syncthreads();
        #pragma unroll
        for (int g = 0; g < 16; ++g) {
            const int le = g * 4 + er4;
            const float v = Tw[le][oc];
            if (base + le < n_nodes)
                out[(size_t)(base + le) * 64 + ob * 16 + oc] = v;
        }
        __syncthreads();
    }
}

extern "C" void kernel_launch(void* const* d_in, const int* in_sizes, int n_in,
                              void* d_out, int out_size, void* d_ws, size_t ws_size,
                              hipStream_t stream) {
    // setup_inputs() order:
    // 0 node_features[N,64] f32, 1 edge_features[E,16] f32, 2 edge_index[2,E] i32,
    // 3 w_m1[80,64], 4 b_m1, 5 w_m2[64,64], 6 b_m2,
    // 7 w_u1[128,64], 8 b_u1, 9 w_u2[64,64], 10 b_u2   (all f32)
    const float* nodef = (const float*)d_in[0];
    const float* edgef = (const float*)d_in[1];
    const int*   eidx  = (const int*)d_in[2];
    const float* w_m1  = (const float*)d_in[3];
    const float* b_m1  = (const float*)d_in[4];
    const float* w_m2  = (const float*)d_in[5];
    const float* b_m2  = (const float*)d_in[6];
    const float* w_u1  = (const float*)d_in[7];
    const float* b_u1  = (const float*)d_in[8];
    const float* w_u2  = (const float*)d_in[9];
    const float* b_u2  = (const float*)d_in[10];
    float* out = (float*)d_out;

    const int n_nodes = out_size / 64;
    const int n_edges = in_sizes[2] / 2;

    fprintf(stderr, "[KL] f32 staged lane-per-edge E=%d N=%d ws=%zu\n",
            n_edges, n_nodes, ws_size);
    fflush(stderr);

    // agg[N,64] f32 in workspace (12.8 MB; ws is 320 MB)
    float* agg = (float*)d_ws;
    hipMemsetAsync(agg, 0, (size_t)n_nodes * 64 * sizeof(float), stream);

    const int blocks_e = (n_edges + THREADS - 1) / THREADS;   // 256 edges/block
    GraphMessagePassing_5952824672257_kernel<<<blocks_e, THREADS, 0, stream>>>(
        nodef, edgef, eidx, w_m1, b_m1, w_m2, b_m2, agg, n_edges, n_nodes);

    const int blocks_n = (n_nodes + THREADS - 1) / THREADS;
    node_mlp_reg<<<blocks_n, THREADS, 0, stream>>>(
        nodef, agg, w_u1, b_u1, w_u2, b_u2, out, n_nodes);

    hipError_t le = hipGetLastError();
    fprintf(stderr, "[KL] last=%d(%s)\n", (int)le, hipGetErrorName(le));
    fflush(stderr);
}

// Round 4
// 564.439 us; speedup vs baseline: 5.7015x; 5.7015x over previous
//
#include <hip/hip_runtime.h>
#include <cstdio>

// ---------------------------------------------------------------------------
// GraphMessagePassing, f32. Round-4: 2-wave cooperative blocks.
//  - block = 128 threads = 2 waves, processes 64 edges (nodes)
//  - lane = edge; wave w owns output channels [w*32, w*32+32)
//    -> h[32] accumulators per lane (no spill; VGPR ~70)
//    -> weight row slice = 32 uniform dwords per k-step (fits SGPR file,
//       s_load broadcast; the R2/R3 spill came from 64-256-dword windows)
//  - activations staged coalesced into shared X[16][65] chunks;
//    inner loop: 1 conflict-free ds_read_b32 : 32 FMA
//  - H[64][65] LDS holds layer-1 output (both halves), reused as the
//    transpose tile for 64B-segment coalesced atomics
// ---------------------------------------------------------------------------

#define TPB 128

__global__ __launch_bounds__(TPB)
void GraphMessagePassing_5952824672257_kernel(
    const float* __restrict__ nodef,   // [N,64]
    const float* __restrict__ edgef,   // [E,16]
    const int*   __restrict__ eidx,    // [2,E] int32
    const float* __restrict__ w1,      // [80,64] row-major
    const float* __restrict__ b1,      // [64]
    const float* __restrict__ w2,      // [64,64]
    const float* __restrict__ b2,      // [64]
    float* __restrict__ agg,           // [N,64] pre-zeroed
    int n_edges, int n_nodes)
{
    __shared__ float X[16][65];        // staged activation chunk [feat][edge]
    __shared__ float H[64][65];        // layer-1 output / transpose tile
    __shared__ int   SI[64];
    __shared__ int   DI[64];

    const int tid  = threadIdx.x;
    const int lane = tid & 63;
    const int wch  = __builtin_amdgcn_readfirstlane((tid >> 6) & 1) * 32;

    const long base = (long)blockIdx.x * 64;

    if (tid < 64) {
        long e  = base + tid;
        long ec = (e < n_edges) ? e : (long)n_edges - 1;
        int s  = eidx[ec];
        int dd = eidx[(size_t)n_edges + ec];
        SI[tid] = ((unsigned)s  < (unsigned)n_nodes) ? s  : 0;
        DI[tid] = ((unsigned)dd < (unsigned)n_nodes) ? dd : 0;
    }
    __syncthreads();

    // staging roles: thread supplies feature r of edges e0, e0+8, ...
    const int r  = tid & 15;
    const int e0 = tid >> 4;           // 0..7
    int se[8];
    #pragma unroll
    for (int i = 0; i < 8; ++i) se[i] = SI[e0 + i * 8];
    const int dreg = DI[lane];         // dst of this lane's edge

    // ---- layer 1: h[c] = b1[wch+c] + sum_k x[k] * w1[k][wch+c], k=0..79
    float h[32];
    #pragma unroll
    for (int c = 0; c < 32; ++c) h[c] = b1[wch + c];     // uniform -> s_load

    #pragma unroll 1
    for (int kc = 0; kc < 5; ++kc) {
        if (kc < 4) {
            #pragma unroll
            for (int i = 0; i < 8; ++i)
                X[r][e0 + i * 8] = nodef[(size_t)se[i] * 64 + kc * 16 + r];
        } else {
            #pragma unroll
            for (int i = 0; i < 8; ++i) {
                int flat = i * 128 + tid;          // 0..1023
                int e  = flat >> 4, rr = flat & 15;
                long ee = base + e; if (ee >= n_edges) ee = n_edges - 1;
                X[rr][e] = edgef[(size_t)ee * 16 + rr];
            }
        }
        __syncthreads();
        #pragma unroll 2
        for (int r2 = 0; r2 < 16; ++r2) {
            const float xk = X[r2][lane];                          // 2-way, free
            const float* __restrict__ wr = w1 + (kc * 16 + r2) * 64 + wch;
            #pragma unroll
            for (int c = 0; c < 32; ++c) h[c] = fmaf(xk, wr[c], h[c]);
        }
        __syncthreads();
    }

    // relu -> H[lane][wch..]   (b32 writes, (lane+c) banks: 2-way, free)
    #pragma unroll
    for (int c = 0; c < 32; ++c) H[lane][wch + c] = fmaxf(h[c], 0.f);
    __syncthreads();

    // ---- layer 2: m[c] = b2[wch+c] + sum_t H[lane][t] * w2[t][wch+c]
    float m[32];
    #pragma unroll
    for (int c = 0; c < 32; ++c) m[c] = b2[wch + c];
    #pragma unroll 2
    for (int t = 0; t < 64; ++t) {
        const float xt = H[lane][t];
        const float* __restrict__ wr = w2 + t * 64 + wch;
        #pragma unroll
        for (int c = 0; c < 32; ++c) m[c] = fmaf(xt, wr[c], m[c]);
    }
    __syncthreads();                   // everyone done reading H

    // reuse H as transpose tile: H[e][wch+c] = m[c]
    #pragma unroll
    for (int c = 0; c < 32; ++c) H[lane][wch + c] = m[c];
    __syncthreads();

    // ---- scatter: per instr 16 edges x 16 consecutive channels (64B segs)
    const int oc  = lane & 15;
    const int er4 = lane >> 4;
    int dgs[16];
    #pragma unroll
    for (int g = 0; g < 16; ++g) dgs[g] = __shfl(dreg, g * 4 + er4, 64);

    #pragma unroll 1
    for (int ob2 = 0; ob2 < 2; ++ob2) {
        #pragma unroll
        for (int g = 0; g < 16; ++g) {
            const int le = g * 4 + er4;
            const float v = H[le][wch + ob2 * 16 + oc];
            if (base + le < n_edges)
                atomicAdd(agg + (size_t)dgs[g] * 64 + wch + ob2 * 16 + oc, v);
        }
    }
}

// Node phase: out = relu(b1 + [node, agg] @ w_u1) @ w_u2 + b_u2
__global__ __launch_bounds__(TPB)
void node_mlp_coop(
    const float* __restrict__ nodef,   // [N,64]
    const float* __restrict__ agg,     // [N,64]
    const float* __restrict__ w1,      // [128,64]
    const float* __restrict__ b1,      // [64]
    const float* __restrict__ w2,      // [64,64]
    const float* __restrict__ b2,      // [64]
    float* __restrict__ out,           // [N,64]
    int n_nodes)
{
    __shared__ float X[16][65];
    __shared__ float H[64][65];

    const int tid  = threadIdx.x;
    const int lane = tid & 63;
    const int wch  = __builtin_amdgcn_readfirstlane((tid >> 6) & 1) * 32;

    const long base = (long)blockIdx.x * 64;

    const int r  = tid & 15;
    const int e0 = tid >> 4;

    float h[32];
    #pragma unroll
    for (int c = 0; c < 32; ++c) h[c] = b1[wch + c];

    // k = 0..127: chunks 0-3 from nodef, 4-7 from agg (rows contiguous)
    #pragma unroll 1
    for (int kc = 0; kc < 8; ++kc) {
        const float* __restrict__ src = (kc < 4) ? nodef : agg;
        const int ko = (kc & 3) * 16;
        #pragma unroll
        for (int i = 0; i < 8; ++i) {
            long row = base + e0 + i * 8;
            if (row >= n_nodes) row = n_nodes - 1;
            X[r][e0 + i * 8] = src[(size_t)row * 64 + ko + r];
        }
        __syncthreads();
        #pragma unroll 2
        for (int r2 = 0; r2 < 16; ++r2) {
            const float xk = X[r2][lane];
            const float* __restrict__ wr = w1 + (kc * 16 + r2) * 64 + wch;
            #pragma unroll
            for (int c = 0; c < 32; ++c) h[c] = fmaf(xk, wr[c], h[c]);
        }
        __syncthreads();
    }

    #pragma unroll
    for (int c = 0; c < 32; ++c) H[lane][wch + c] = fmaxf(h[c], 0.f);
    __syncthreads();

    float m[32];
    #pragma unroll
    for (int c = 0; c < 32; ++c) m[c] = b2[wch + c];
    #pragma unroll 2
    for (int t = 0; t < 64; ++t) {
        const float xt = H[lane][t];
        const float* __restrict__ wr = w2 + t * 64 + wch;
        #pragma unroll
        for (int c = 0; c < 32; ++c) m[c] = fmaf(xt, wr[c], m[c]);
    }
    __syncthreads();

    #pragma unroll
    for (int c = 0; c < 32; ++c) H[lane][wch + c] = m[c];
    __syncthreads();

    const int oc  = lane & 15;
    const int er4 = lane >> 4;
    #pragma unroll 1
    for (int ob2 = 0; ob2 < 2; ++ob2) {
        #pragma unroll
        for (int g = 0; g < 16; ++g) {
            const int le = g * 4 + er4;
            const float v = H[le][wch + ob2 * 16 + oc];
            if (base + le < n_nodes)
                out[(size_t)(base + le) * 64 + wch + ob2 * 16 + oc] = v;
        }
    }
}

extern "C" void kernel_launch(void* const* d_in, const int* in_sizes, int n_in,
                              void* d_out, int out_size, void* d_ws, size_t ws_size,
                              hipStream_t stream) {
    // setup_inputs() order:
    // 0 node_features[N,64] f32, 1 edge_features[E,16] f32, 2 edge_index[2,E] i32,
    // 3 w_m1[80,64], 4 b_m1, 5 w_m2[64,64], 6 b_m2,
    // 7 w_u1[128,64], 8 b_u1, 9 w_u2[64,64], 10 b_u2   (all f32)
    const float* nodef = (const float*)d_in[0];
    const float* edgef = (const float*)d_in[1];
    const int*   eidx  = (const int*)d_in[2];
    const float* w_m1  = (const float*)d_in[3];
    const float* b_m1  = (const float*)d_in[4];
    const float* w_m2  = (const float*)d_in[5];
    const float* b_m2  = (const float*)d_in[6];
    const float* w_u1  = (const float*)d_in[7];
    const float* b_u1  = (const float*)d_in[8];
    const float* w_u2  = (const float*)d_in[9];
    const float* b_u2  = (const float*)d_in[10];
    float* out = (float*)d_out;

    const int n_nodes = out_size / 64;
    const int n_edges = in_sizes[2] / 2;

    fprintf(stderr, "[KL] f32 2-wave-coop E=%d N=%d ws=%zu\n",
            n_edges, n_nodes, ws_size);
    fflush(stderr);

    // agg[N,64] f32 in workspace (12.8 MB; ws is 320 MB)
    float* agg = (float*)d_ws;
    hipMemsetAsync(agg, 0, (size_t)n_nodes * 64 * sizeof(float), stream);

    const int blocks_e = (n_edges + 63) / 64;    // 64 edges per 128-thr block
    GraphMessagePassing_5952824672257_kernel<<<blocks_e, TPB, 0, stream>>>(
        nodef, edgef, eidx, w_m1, b_m1, w_m2, b_m2, agg, n_edges, n_nodes);

    const int blocks_n = (n_nodes + 63) / 64;
    node_mlp_coop<<<blocks_n, TPB, 0, stream>>>(
        nodef, agg, w_u1, b_u1, w_u2, b_u2, out, n_nodes);

    hipError_t le = hipGetLastError();
    fprintf(stderr, "[KL] last=%d(%s)\n", (int)le, hipGetErrorName(le));
    fflush(stderr);
}

// Round 6
// 481.611 us; speedup vs baseline: 6.6821x; 1.1720x over previous
//
#include <hip/hip_runtime.h>
#include <cstdio>

// ---------------------------------------------------------------------------
// GraphMessagePassing, f32. Round-6 = Round-5 resubmit (infra failure, no
// counters returned; source re-audited, no fault/hang hazard found).
//  - block = 256 threads = 4 waves, 64 edges/block; lane = edge
//  - wave w owns output channels [w*16, w*16+16) -> h[16] accumulators,
//    weight window 4x16 = 64 uniform dwords (proven no-spill in R4)
//  - X staging tile ALIASED into H rows 0..15 (barrier-separated lifetimes):
//    LDS ~17 KB => 8 blocks/CU * 4 waves = 32 waves/CU (100% occupancy)
//  - inner loop: 1 conflict-free ds_read_b32 : 16 FMA, s_load weights
//  - scatter: DI[] LDS broadcast for dsts; 64B-segment coalesced atomics
// ---------------------------------------------------------------------------

#define TPB 256

__global__ __launch_bounds__(TPB)
void GraphMessagePassing_5952824672257_kernel(
    const float* __restrict__ nodef,   // [N,64]
    const float* __restrict__ edgef,   // [E,16]
    const int*   __restrict__ eidx,    // [2,E] int32
    const float* __restrict__ w1,      // [80,64] row-major
    const float* __restrict__ b1,      // [64]
    const float* __restrict__ w2,      // [64,64]
    const float* __restrict__ b2,      // [64]
    float* __restrict__ agg,           // [N,64] pre-zeroed
    int n_edges, int n_nodes)
{
    __shared__ float HB[64][65];       // X (rows 0..15) aliased with H (full)
    __shared__ int   SI[64];
    __shared__ int   DI[64];

    const int tid  = threadIdx.x;
    const int lane = tid & 63;
    const int wch  = __builtin_amdgcn_readfirstlane(tid >> 6) * 16; // 0/16/32/48

    const long base = (long)blockIdx.x * 64;

    if (tid < 64) {
        long e  = base + tid;
        long ec = (e < n_edges) ? e : (long)n_edges - 1;
        if (ec < 0) ec = 0;
        int s  = eidx[ec];
        int dd = eidx[(size_t)n_edges + ec];
        SI[tid] = ((unsigned)s  < (unsigned)n_nodes) ? s  : 0;
        DI[tid] = ((unsigned)dd < (unsigned)n_nodes) ? dd : 0;
    }
    __syncthreads();

    // staging roles: thread supplies feature r of edges e0, e0+16, e0+32, e0+48
    const int r  = tid & 15;
    const int e0 = tid >> 4;           // 0..15
    int se[4];
    #pragma unroll
    for (int i = 0; i < 4; ++i) se[i] = SI[e0 + i * 16];

    // ---- layer 1: h[c] = b1[wch+c] + sum_k x[k] * w1[k][wch+c], k=0..79
    float h[16];
    #pragma unroll
    for (int c = 0; c < 16; ++c) h[c] = b1[wch + c];     // uniform -> s_load

    #pragma unroll 1
    for (int kc = 0; kc < 5; ++kc) {
        if (kc < 4) {
            #pragma unroll
            for (int i = 0; i < 4; ++i)
                HB[r][e0 + i * 16] = nodef[(size_t)se[i] * 64 + kc * 16 + r];
        } else {
            #pragma unroll
            for (int i = 0; i < 4; ++i) {
                int flat = i * 256 + tid;          // 0..1023
                int e  = flat >> 4, rr = flat & 15;
                long ee = base + e;
                if (ee >= n_edges) ee = n_edges - 1;
                if (ee < 0) ee = 0;
                HB[rr][e] = edgef[(size_t)ee * 16 + rr];
            }
        }
        __syncthreads();
        #pragma unroll 4
        for (int r2 = 0; r2 < 16; ++r2) {
            const float xk = HB[r2][lane];                     // 2-way, free
            const float* __restrict__ wr = w1 + (kc * 16 + r2) * 64 + wch;
            #pragma unroll
            for (int c = 0; c < 16; ++c) h[c] = fmaf(xk, wr[c], h[c]);
        }
        __syncthreads();
    }

    // relu -> H[lane][wch..] (X fully consumed; aliasing safe past barrier)
    #pragma unroll
    for (int c = 0; c < 16; ++c) HB[lane][wch + c] = fmaxf(h[c], 0.f);
    __syncthreads();

    // ---- layer 2: m[c] = b2[wch+c] + sum_t H[lane][t] * w2[t][wch+c]
    float m[16];
    #pragma unroll
    for (int c = 0; c < 16; ++c) m[c] = b2[wch + c];
    #pragma unroll 4
    for (int t = 0; t < 64; ++t) {
        const float xt = HB[lane][t];
        const float* __restrict__ wr = w2 + t * 64 + wch;
        #pragma unroll
        for (int c = 0; c < 16; ++c) m[c] = fmaf(xt, wr[c], m[c]);
    }
    __syncthreads();                   // everyone done reading H

    // reuse H as transpose tile: H[edge][ch]
    #pragma unroll
    for (int c = 0; c < 16; ++c) HB[lane][wch + c] = m[c];
    __syncthreads();

    // ---- scatter: per instr 4 edges x 16 consecutive channels (64B segs)
    const int oc  = lane & 15;
    const int er4 = lane >> 4;
    #pragma unroll
    for (int g = 0; g < 16; ++g) {
        const int le = g * 4 + er4;
        const int dg = DI[le];                     // 4-addr LDS broadcast
        const float v = HB[le][wch + oc];
        if (base + le < n_edges)
            atomicAdd(agg + (size_t)dg * 64 + wch + oc, v);
    }
}

// Node phase: out = relu(b1 + [node, agg] @ w_u1) @ w_u2 + b_u2
__global__ __launch_bounds__(TPB)
void node_mlp_coop(
    const float* __restrict__ nodef,   // [N,64]
    const float* __restrict__ agg,     // [N,64]
    const float* __restrict__ w1,      // [128,64]
    const float* __restrict__ b1,      // [64]
    const float* __restrict__ w2,      // [64,64]
    const float* __restrict__ b2,      // [64]
    float* __restrict__ out,           // [N,64]
    int n_nodes)
{
    __shared__ float HB[64][65];

    const int tid  = threadIdx.x;
    const int lane = tid & 63;
    const int wch  = __builtin_amdgcn_readfirstlane(tid >> 6) * 16;

    const long base = (long)blockIdx.x * 64;

    const int r  = tid & 15;
    const int e0 = tid >> 4;

    float h[16];
    #pragma unroll
    for (int c = 0; c < 16; ++c) h[c] = b1[wch + c];

    // k = 0..127: chunks 0-3 from nodef, 4-7 from agg (rows contiguous)
    #pragma unroll 1
    for (int kc = 0; kc < 8; ++kc) {
        const float* __restrict__ src = (kc < 4) ? nodef : agg;
        const int ko = (kc & 3) * 16;
        #pragma unroll
        for (int i = 0; i < 4; ++i) {
            long row = base + e0 + i * 16;
            if (row >= n_nodes) row = n_nodes - 1;
            if (row < 0) row = 0;
            HB[r][e0 + i * 16] = src[(size_t)row * 64 + ko + r];
        }
        __syncthreads();
        #pragma unroll 4
        for (int r2 = 0; r2 < 16; ++r2) {
            const float xk = HB[r2][lane];
            const float* __restrict__ wr = w1 + (kc * 16 + r2) * 64 + wch;
            #pragma unroll
            for (int c = 0; c < 16; ++c) h[c] = fmaf(xk, wr[c], h[c]);
        }
        __syncthreads();
    }

    #pragma unroll
    for (int c = 0; c < 16; ++c) HB[lane][wch + c] = fmaxf(h[c], 0.f);
    __syncthreads();

    float m[16];
    #pragma unroll
    for (int c = 0; c < 16; ++c) m[c] = b2[wch + c];
    #pragma unroll 4
    for (int t = 0; t < 64; ++t) {
        const float xt = HB[lane][t];
        const float* __restrict__ wr = w2 + t * 64 + wch;
        #pragma unroll
        for (int c = 0; c < 16; ++c) m[c] = fmaf(xt, wr[c], m[c]);
    }
    __syncthreads();

    #pragma unroll
    for (int c = 0; c < 16; ++c) HB[lane][wch + c] = m[c];
    __syncthreads();

    const int oc  = lane & 15;
    const int er4 = lane >> 4;
    #pragma unroll
    for (int g = 0; g < 16; ++g) {
        const int le = g * 4 + er4;
        const float v = HB[le][wch + oc];
        if (base + le < n_nodes)
            out[(size_t)(base + le) * 64 + wch + oc] = v;
    }
}

extern "C" void kernel_launch(void* const* d_in, const int* in_sizes, int n_in,
                              void* d_out, int out_size, void* d_ws, size_t ws_size,
                              hipStream_t stream) {
    // setup_inputs() order:
    // 0 node_features[N,64] f32, 1 edge_features[E,16] f32, 2 edge_index[2,E] i32,
    // 3 w_m1[80,64], 4 b_m1, 5 w_m2[64,64], 6 b_m2,
    // 7 w_u1[128,64], 8 b_u1, 9 w_u2[64,64], 10 b_u2   (all f32)
    const float* nodef = (const float*)d_in[0];
    const float* edgef = (const float*)d_in[1];
    const int*   eidx  = (const int*)d_in[2];
    const float* w_m1  = (const float*)d_in[3];
    const float* b_m1  = (const float*)d_in[4];
    const float* w_m2  = (const float*)d_in[5];
    const float* b_m2  = (const float*)d_in[6];
    const float* w_u1  = (const float*)d_in[7];
    const float* b_u1  = (const float*)d_in[8];
    const float* w_u2  = (const float*)d_in[9];
    const float* b_u2  = (const float*)d_in[10];
    float* out = (float*)d_out;

    const int n_nodes = out_size / 64;
    const int n_edges = in_sizes[2] / 2;
    if (n_edges <= 0 || n_nodes <= 0) return;

    fprintf(stderr, "[KL] f32 4-wave-coop E=%d N=%d ws=%zu\n",
            n_edges, n_nodes, ws_size);
    fflush(stderr);

    // agg[N,64] f32 in workspace (12.8 MB; ws is 320 MB)
    float* agg = (float*)d_ws;
    hipMemsetAsync(agg, 0, (size_t)n_nodes * 64 * sizeof(float), stream);

    const int blocks_e = (n_edges + 63) / 64;    // 64 edges per 256-thr block
    GraphMessagePassing_5952824672257_kernel<<<blocks_e, TPB, 0, stream>>>(
        nodef, edgef, eidx, w_m1, b_m1, w_m2, b_m2, agg, n_edges, n_nodes);

    const int blocks_n = (n_nodes + 63) / 64;
    node_mlp_coop<<<blocks_n, TPB, 0, stream>>>(
        nodef, agg, w_u1, b_u1, w_u2, b_u2, out, n_nodes);

    hipError_t le = hipGetLastError();
    fprintf(stderr, "[KL] last=%d(%s)\n", (int)le, hipGetErrorName(le));
    fflush(stderr);
}

// Round 7
// 465.014 us; speedup vs baseline: 6.9206x; 1.0357x over previous
//
#include <hip/hip_runtime.h>
#include <cstdio>

// ---------------------------------------------------------------------------
// GraphMessagePassing, f32. Round-7: R6 structure + double-buffered staging.
//  - block = 256 threads = 4 waves, 64 edges/block; lane = edge
//  - wave w owns output channels [w*16, w*16+16): h[16], 64-dword weight
//    window, s_load-broadcast weights (proven no-spill, VGPR 28 in R6)
//  - X double-buffer ALIASED into the H tile (X dead before H written):
//    LDS stays 17 KB -> 8 blocks/CU = 32 waves/CU
//  - pipeline per k-chunk: compute(cur) || loads(kc+2) in flight;
//    ds_write(kc+1 -> cur^1); ONE barrier (was two) -> stall gap shrinks
//  - scatter: DI[] broadcast dsts; 64B-segment coalesced atomics
// ---------------------------------------------------------------------------

#define TPB 256

__global__ __launch_bounds__(TPB)
void GraphMessagePassing_5952824672257_kernel(
    const float* __restrict__ nodef,   // [N,64]
    const float* __restrict__ edgef,   // [E,16]
    const int*   __restrict__ eidx,    // [2,E] int32
    const float* __restrict__ w1,      // [80,64] row-major
    const float* __restrict__ b1,      // [64]
    const float* __restrict__ w2,      // [64,64]
    const float* __restrict__ b2,      // [64]
    float* __restrict__ agg,           // [N,64] pre-zeroed
    int n_edges, int n_nodes)
{
    __shared__ float HB[64][65];       // H tile; X dbuf aliased into it
    __shared__ int   SI[64];
    __shared__ int   DI[64];
    float* __restrict__ Xf = &HB[0][0];   // X(buf,r,e) = Xf[buf*1056 + r*66 + e]

    const int tid  = threadIdx.x;
    const int lane = tid & 63;
    const int wch  = __builtin_amdgcn_readfirstlane(tid >> 6) * 16; // 0/16/32/48

    const long base = (long)blockIdx.x * 64;

    if (tid < 64) {
        long e  = base + tid;
        long ec = (e < n_edges) ? e : (long)n_edges - 1;
        if (ec < 0) ec = 0;
        int s  = eidx[ec];
        int dd = eidx[(size_t)n_edges + ec];
        SI[tid] = ((unsigned)s  < (unsigned)n_nodes) ? s  : 0;
        DI[tid] = ((unsigned)dd < (unsigned)n_nodes) ? dd : 0;
    }
    __syncthreads();

    // staging roles: thread supplies feature r of edges e0, e0+16, +32, +48
    const int r  = tid & 15;
    const int e0 = tid >> 4;           // 0..15
    int se[4];
    #pragma unroll
    for (int i = 0; i < 4; ++i) se[i] = SI[e0 + i * 16];

    // chunk-4 (edge features) repartition: flat 1024-element copy
    int    xoff4[4];
    size_t goff4[4];
    #pragma unroll
    for (int i = 0; i < 4; ++i) {
        int flat = i * 256 + tid;              // 0..1023
        int e = flat >> 4, rr = flat & 15;
        long ee = base + e;
        if (ee >= n_edges) ee = n_edges - 1;
        if (ee < 0) ee = 0;
        xoff4[i] = rr * 66 + e;
        goff4[i] = (size_t)ee * 16 + rr;
    }

    float h[16];
    #pragma unroll
    for (int c = 0; c < 16; ++c) h[c] = b1[wch + c];     // uniform -> s_load

    // ---- pipeline prologue: chunk0 -> buf0; chunk1 loads in flight
    float pf[4];
    #pragma unroll
    for (int i = 0; i < 4; ++i) pf[i] = nodef[(size_t)se[i] * 64 + r];
    #pragma unroll
    for (int i = 0; i < 4; ++i) Xf[r * 66 + e0 + i * 16] = pf[i];
    #pragma unroll
    for (int i = 0; i < 4; ++i) pf[i] = nodef[(size_t)se[i] * 64 + 16 + r];
    __syncthreads();

    // ---- layer 1 main loop: 1 barrier / chunk, loads overlap compute
    #pragma unroll
    for (int kc = 0; kc < 5; ++kc) {
        const int cur = kc & 1;
        #pragma unroll 4
        for (int r2 = 0; r2 < 16; ++r2) {
            const float xk = Xf[cur * 1056 + r2 * 66 + lane];  // conflict-free
            const float* __restrict__ wr = w1 + (kc * 16 + r2) * 64 + wch;
            #pragma unroll
            for (int c = 0; c < 16; ++c) h[c] = fmaf(xk, wr[c], h[c]);
        }
        if (kc < 4) {
            // store prefetched chunk kc+1 into the other buffer
            if (kc == 3) {
                #pragma unroll
                for (int i = 0; i < 4; ++i)
                    Xf[(cur ^ 1) * 1056 + xoff4[i]] = pf[i];
            } else {
                #pragma unroll
                for (int i = 0; i < 4; ++i)
                    Xf[(cur ^ 1) * 1056 + r * 66 + e0 + i * 16] = pf[i];
            }
            // issue loads for chunk kc+2
            if (kc == 2) {
                #pragma unroll
                for (int i = 0; i < 4; ++i) pf[i] = edgef[goff4[i]];
            } else if (kc < 2) {
                #pragma unroll
                for (int i = 0; i < 4; ++i)
                    pf[i] = nodef[(size_t)se[i] * 64 + (kc + 2) * 16 + r];
            }
            __syncthreads();
        }
    }
    __syncthreads();   // all waves done reading X alias before H is written

    // relu -> H[lane][wch..]
    #pragma unroll
    for (int c = 0; c < 16; ++c) HB[lane][wch + c] = fmaxf(h[c], 0.f);
    __syncthreads();

    // ---- layer 2: m[c] = b2[wch+c] + sum_t H[lane][t] * w2[t][wch+c]
    float m[16];
    #pragma unroll
    for (int c = 0; c < 16; ++c) m[c] = b2[wch + c];
    #pragma unroll 4
    for (int t = 0; t < 64; ++t) {
        const float xt = HB[lane][t];                  // 2-way, free
        const float* __restrict__ wr = w2 + t * 64 + wch;
        #pragma unroll
        for (int c = 0; c < 16; ++c) m[c] = fmaf(xt, wr[c], m[c]);
    }
    __syncthreads();                   // everyone done reading H

    // reuse H as transpose tile: H[edge][ch]
    #pragma unroll
    for (int c = 0; c < 16; ++c) HB[lane][wch + c] = m[c];
    __syncthreads();

    // ---- scatter: per instr 4 edges x 16 consecutive channels (64B segs)
    const int oc  = lane & 15;
    const int er4 = lane >> 4;
    #pragma unroll
    for (int g = 0; g < 16; ++g) {
        const int le = g * 4 + er4;
        const int dg = DI[le];                     // 4-addr LDS broadcast
        const float v = HB[le][wch + oc];
        if (base + le < n_edges)
            atomicAdd(agg + (size_t)dg * 64 + wch + oc, v);
    }
}

// Node phase: out = relu(b1 + [node, agg] @ w_u1) @ w_u2 + b_u2
__global__ __launch_bounds__(TPB)
void node_mlp_coop(
    const float* __restrict__ nodef,   // [N,64]
    const float* __restrict__ agg,     // [N,64]
    const float* __restrict__ w1,      // [128,64]
    const float* __restrict__ b1,      // [64]
    const float* __restrict__ w2,      // [64,64]
    const float* __restrict__ b2,      // [64]
    float* __restrict__ out,           // [N,64]
    int n_nodes)
{
    __shared__ float HB[64][65];
    float* __restrict__ Xf = &HB[0][0];

    const int tid  = threadIdx.x;
    const int lane = tid & 63;
    const int wch  = __builtin_amdgcn_readfirstlane(tid >> 6) * 16;

    const long base = (long)blockIdx.x * 64;

    const int r  = tid & 15;
    const int e0 = tid >> 4;
    size_t rows[4];
    #pragma unroll
    for (int i = 0; i < 4; ++i) {
        long row = base + e0 + i * 16;
        if (row >= n_nodes) row = n_nodes - 1;
        if (row < 0) row = 0;
        rows[i] = (size_t)row * 64;
    }

    float h[16];
    #pragma unroll
    for (int c = 0; c < 16; ++c) h[c] = b1[wch + c];

    // prologue: chunk0 -> buf0; chunk1 in flight
    float pf[4];
    #pragma unroll
    for (int i = 0; i < 4; ++i) pf[i] = nodef[rows[i] + r];
    #pragma unroll
    for (int i = 0; i < 4; ++i) Xf[r * 66 + e0 + i * 16] = pf[i];
    #pragma unroll
    for (int i = 0; i < 4; ++i) pf[i] = nodef[rows[i] + 16 + r];
    __syncthreads();

    // k = 0..127: chunks 0-3 nodef, 4-7 agg
    #pragma unroll
    for (int kc = 0; kc < 8; ++kc) {
        const int cur = kc & 1;
        #pragma unroll 4
        for (int r2 = 0; r2 < 16; ++r2) {
            const float xk = Xf[cur * 1056 + r2 * 66 + lane];
            const float* __restrict__ wr = w1 + (kc * 16 + r2) * 64 + wch;
            #pragma unroll
            for (int c = 0; c < 16; ++c) h[c] = fmaf(xk, wr[c], h[c]);
        }
        if (kc < 7) {
            #pragma unroll
            for (int i = 0; i < 4; ++i)
                Xf[(cur ^ 1) * 1056 + r * 66 + e0 + i * 16] = pf[i];
            if (kc < 6) {
                const float* __restrict__ src = (kc + 2 < 4) ? nodef : agg;
                const int ko = ((kc + 2) & 3) * 16;
                #pragma unroll
                for (int i = 0; i < 4; ++i) pf[i] = src[rows[i] + ko + r];
            }
            __syncthreads();
        }
    }
    __syncthreads();   // X alias dead before H write

    #pragma unroll
    for (int c = 0; c < 16; ++c) HB[lane][wch + c] = fmaxf(h[c], 0.f);
    __syncthreads();

    float m[16];
    #pragma unroll
    for (int c = 0; c < 16; ++c) m[c] = b2[wch + c];
    #pragma unroll 4
    for (int t = 0; t < 64; ++t) {
        const float xt = HB[lane][t];
        const float* __restrict__ wr = w2 + t * 64 + wch;
        #pragma unroll
        for (int c = 0; c < 16; ++c) m[c] = fmaf(xt, wr[c], m[c]);
    }
    __syncthreads();

    #pragma unroll
    for (int c = 0; c < 16; ++c) HB[lane][wch + c] = m[c];
    __syncthreads();

    const int oc  = lane & 15;
    const int er4 = lane >> 4;
    #pragma unroll
    for (int g = 0; g < 16; ++g) {
        const int le = g * 4 + er4;
        const float v = HB[le][wch + oc];
        if (base + le < n_nodes)
            out[(size_t)(base + le) * 64 + wch + oc] = v;
    }
}

extern "C" void kernel_launch(void* const* d_in, const int* in_sizes, int n_in,
                              void* d_out, int out_size, void* d_ws, size_t ws_size,
                              hipStream_t stream) {
    // setup_inputs() order:
    // 0 node_features[N,64] f32, 1 edge_features[E,16] f32, 2 edge_index[2,E] i32,
    // 3 w_m1[80,64], 4 b_m1, 5 w_m2[64,64], 6 b_m2,
    // 7 w_u1[128,64], 8 b_u1, 9 w_u2[64,64], 10 b_u2   (all f32)
    const float* nodef = (const float*)d_in[0];
    const float* edgef = (const float*)d_in[1];
    const int*   eidx  = (const int*)d_in[2];
    const float* w_m1  = (const float*)d_in[3];
    const float* b_m1  = (const float*)d_in[4];
    const float* w_m2  = (const float*)d_in[5];
    const float* b_m2  = (const float*)d_in[6];
    const float* w_u1  = (const float*)d_in[7];
    const float* b_u1  = (const float*)d_in[8];
    const float* w_u2  = (const float*)d_in[9];
    const float* b_u2  = (const float*)d_in[10];
    float* out = (float*)d_out;

    const int n_nodes = out_size / 64;
    const int n_edges = in_sizes[2] / 2;
    if (n_edges <= 0 || n_nodes <= 0) return;

    fprintf(stderr, "[KL] f32 4-wave-coop dbuf E=%d N=%d ws=%zu\n",
            n_edges, n_nodes, ws_size);
    fflush(stderr);

    // agg[N,64] f32 in workspace (12.8 MB; ws is 320 MB)
    float* agg = (float*)d_ws;
    hipMemsetAsync(agg, 0, (size_t)n_nodes * 64 * sizeof(float), stream);

    const int blocks_e = (n_edges + 63) / 64;    // 64 edges per 256-thr block
    GraphMessagePassing_5952824672257_kernel<<<blocks_e, TPB, 0, stream>>>(
        nodef, edgef, eidx, w_m1, b_m1, w_m2, b_m2, agg, n_edges, n_nodes);

    const int blocks_n = (n_nodes + 63) / 64;
    node_mlp_coop<<<blocks_n, TPB, 0, stream>>>(
        nodef, agg, w_u1, b_u1, w_u2, b_u2, out, n_nodes);

    hipError_t le = hipGetLastError();
    fprintf(stderr, "[KL] last=%d(%s)\n", (int)le, hipGetErrorName(le));
    fflush(stderr);
}